// Round 1
// baseline (630.816 us; speedup 1.0000x reference)
//
#include <hip/hip_runtime.h>

#define Bq 2
#define Yq 512
#define Xq 512
#define Cq 128
#define CINq 192
#define NVOX 400000

typedef __bf16 bf16x8 __attribute__((ext_vector_type(8)));
typedef float f32x4 __attribute__((ext_vector_type(4)));
typedef short s16x8 __attribute__((ext_vector_type(8)));

__device__ __forceinline__ short f2bf_s(float f){
    return __builtin_bit_cast(short, static_cast<__bf16>(f));
}

// ---------------- weight transpose + bf16 convert ----------------
// wT[tap][cout][cin]  <- conv_w[ky][kx][cin][cout]   (9*128*128)
// wpT[cout][cin]      <- W_proj[cin][cout]           (128*192)
__global__ void kprep(const float* __restrict__ conv_w, const float* __restrict__ W_proj,
                      short* __restrict__ wT, short* __restrict__ wpT){
    int tid = blockIdx.x*256 + threadIdx.x;
    if (tid < 9*128*128){
        int tap = tid >> 14; int r = tid & 16383; int co = r >> 7; int ci = r & 127;
        wT[tid] = f2bf_s(conv_w[tap*16384 + ci*128 + co]);
    }
    int e = tid - 9*128*128;
    if (e >= 0 && e < 128*192){
        int co = e / 192; int ci = e - co*192;
        wpT[e] = f2bf_s(W_proj[ci*128 + co]);
    }
}

// ---------------- projection + BN1 + ReLU + scatter ----------------
// tile: 64 voxels x 128 couts, 4 waves, wave tile 64x32, K=192 (6 chunks of 32)
__global__ void __launch_bounds__(256, 2)
kproj(const float* __restrict__ vf, const int* __restrict__ vc,
      const short* __restrict__ wpT, const float* __restrict__ bp,
      const float* __restrict__ g1, const float* __restrict__ be1,
      const float* __restrict__ mu1, const float* __restrict__ va1,
      float* __restrict__ dense, unsigned char* __restrict__ act){
    __shared__ short A[64*200];     // [voxel][cin], stride 200 (2-way-free banks)
    __shared__ int cells[64];
    const int t = threadIdx.x;
    const int v0 = blockIdx.x * 64;

    // stage A (fp32 -> bf16): 64*48 float4 = 3072 = 12*256
    const float4* vf4 = reinterpret_cast<const float4*>(vf);
    #pragma unroll
    for (int j = 0; j < 12; ++j){
        int i = t + j*256;
        int v = i / 48, kq = i - v*48;
        float4 x = vf4[(size_t)(v0 + v)*48 + kq];
        short4 s; s.x=f2bf_s(x.x); s.y=f2bf_s(x.y); s.z=f2bf_s(x.z); s.w=f2bf_s(x.w);
        *reinterpret_cast<short4*>(&A[v*200 + kq*4]) = s;
    }
    if (t < 64){
        int vi = v0 + t;
        int bi = vc[vi*4 + 0], yi = vc[vi*4 + 2], xi = vc[vi*4 + 3];
        int cell = (bi*Yq + yi)*Xq + xi;
        cells[t] = cell;
        act[cell] = 1;
    }
    __syncthreads();

    const int w  = t >> 6;
    const int l  = t & 63;
    const int lr = l & 15;
    const int q  = l >> 4;

    // preload all B fragments for this wave's 32 couts (2 n-blocks x 6 k-chunks)
    const short* wp_lane = wpT + (size_t)(w*32 + lr)*192 + q*8;
    bf16x8 bb[2][6];
    #pragma unroll
    for (int n = 0; n < 2; ++n)
        #pragma unroll
        for (int kc = 0; kc < 6; ++kc)
            bb[n][kc] = *reinterpret_cast<const bf16x8*>(wp_lane + n*16*192 + kc*32);

    f32x4 acc[4][2] = {};
    #pragma unroll
    for (int kc = 0; kc < 6; ++kc){
        bf16x8 a[4];
        #pragma unroll
        for (int m = 0; m < 4; ++m)
            a[m] = *reinterpret_cast<const bf16x8*>(&A[(m*16 + lr)*200 + kc*32 + q*8]);
        #pragma unroll
        for (int m = 0; m < 4; ++m)
            #pragma unroll
            for (int n = 0; n < 2; ++n)
                acc[m][n] = __builtin_amdgcn_mfma_f32_16x16x32_bf16(a[m], bb[n][kc], acc[m][n], 0, 0, 0);
    }

    // epilogue: BN1 + ReLU + fp32 atomic scatter
    #pragma unroll
    for (int n = 0; n < 2; ++n){
        int c = w*32 + n*16 + lr;
        float s1  = g1[c] * rsqrtf(va1[c] + 1e-5f);
        float sh1 = be1[c] + (bp[c] - mu1[c]) * s1;
        #pragma unroll
        for (int m = 0; m < 4; ++m){
            #pragma unroll
            for (int r = 0; r < 4; ++r){
                int v = m*16 + q*4 + r;
                float val = fmaxf(fmaf(acc[m][n][r], s1, sh1), 0.f);
                atomicAdd(&dense[(size_t)cells[v]*128 + c], val);
            }
        }
    }
}

// ---------------- pad + fp32 -> bf16 convert ----------------
// dbf layout: [B][Y+2][X+2][C] bf16, zero border
__global__ void kcvt(const float* __restrict__ dense, short* __restrict__ dbf){
    int i = blockIdx.x*256 + threadIdx.x;
    if (i >= 2*514*514*16) return;
    int row = i >> 4; int c8 = i & 15;
    int b  = row / (514*514); int rr = row - b*(514*514);
    int yp = rr / 514; int xp = rr - yp*514;
    s16x8 o = {0,0,0,0,0,0,0,0};
    if (yp >= 1 && yp <= 512 && xp >= 1 && xp <= 512){
        const float4* s = reinterpret_cast<const float4*>(
            &dense[((size_t)((b*Yq + (yp-1))*Xq) + (xp-1))*128 + c8*8]);
        float4 f0 = s[0], f1 = s[1];
        o[0]=f2bf_s(f0.x); o[1]=f2bf_s(f0.y); o[2]=f2bf_s(f0.z); o[3]=f2bf_s(f0.w);
        o[4]=f2bf_s(f1.x); o[5]=f2bf_s(f1.y); o[6]=f2bf_s(f1.z); o[7]=f2bf_s(f1.w);
    }
    *reinterpret_cast<s16x8*>(&dbf[(size_t)row*128 + c8*8]) = o;
}

// ---------------- conv 3x3 + BN2 + ReLU + mask ----------------
// tile: 64 x-positions x 128 couts, 4 waves, wave tile 64x32
// A in LDS [3][66][136] bf16 (stride 136 -> 2-way-free banks); B from L2 (2-tap dbuf)
__global__ void __launch_bounds__(256, 2)
kconv(const short* __restrict__ dbf, const short* __restrict__ wT,
      const unsigned char* __restrict__ act, const float* __restrict__ cb,
      const float* __restrict__ g2, const float* __restrict__ be2,
      const float* __restrict__ mu2, const float* __restrict__ va2,
      float* __restrict__ out){
    __shared__ short A[3*66*136];   // 53,856 B
    const int t   = threadIdx.x;
    const int bid = blockIdx.x;
    const int b   = bid >> 12;
    const int rem = bid & 4095;
    const int y   = rem >> 3;
    const int x0  = (rem & 7) << 6;

    // stage A: 3 rows x 66 pos x 128 ch = 3168 x 16B
    {
        const uint4* src = reinterpret_cast<const uint4*>(dbf);
        #pragma unroll
        for (int j = 0; j < 13; ++j){
            int i = t + j*256;
            if (i < 3168){
                int ky = i / 1056; int r = i - ky*1056;
                int p = r >> 4; int c8 = r & 15;
                size_t s8 = (((size_t)((b*514 + y + ky)*514 + x0))*128 + p*128 + c8*8) >> 3;
                *reinterpret_cast<uint4*>(&A[(ky*66 + p)*136 + c8*8]) = src[s8];
            }
        }
    }
    __syncthreads();

    const int w  = t >> 6;
    const int l  = t & 63;
    const int lr = l & 15;
    const int q  = l >> 4;
    const int aBase = lr*136 + q*8;
    const short* wt_lane = wT + (size_t)(w*32 + lr)*128 + q*8;

    f32x4 acc[4][2] = {};
    bf16x8 bB[2][2][4];   // [buf][n][kc]
    #pragma unroll
    for (int n = 0; n < 2; ++n)
        #pragma unroll
        for (int kc = 0; kc < 4; ++kc)
            bB[0][n][kc] = *reinterpret_cast<const bf16x8*>(wt_lane + n*2048 + kc*32);

    #pragma unroll
    for (int tap = 0; tap < 9; ++tap){
        const int cur = tap & 1, nxt = cur ^ 1;
        if (tap < 8){
            const short* wn = wt_lane + (tap+1)*16384;
            #pragma unroll
            for (int n = 0; n < 2; ++n)
                #pragma unroll
                for (int kc = 0; kc < 4; ++kc)
                    bB[nxt][n][kc] = *reinterpret_cast<const bf16x8*>(wn + n*2048 + kc*32);
        }
        const int ky = tap / 3, kx = tap - ky*3;
        const int tapOff = (ky*66 + kx)*136;
        #pragma unroll
        for (int kc = 0; kc < 4; ++kc){
            bf16x8 a[4];
            #pragma unroll
            for (int m = 0; m < 4; ++m)
                a[m] = *reinterpret_cast<const bf16x8*>(&A[tapOff + m*2176 + aBase + kc*32]);
            #pragma unroll
            for (int m = 0; m < 4; ++m)
                #pragma unroll
                for (int n = 0; n < 2; ++n)
                    acc[m][n] = __builtin_amdgcn_mfma_f32_16x16x32_bf16(a[m], bB[cur][n][kc], acc[m][n], 0, 0, 0);
        }
    }

    // epilogue: BN2 + ReLU + mask
    #pragma unroll
    for (int n = 0; n < 2; ++n){
        int c = w*32 + n*16 + lr;
        float s2  = g2[c] * rsqrtf(va2[c] + 1e-3f);
        float sh2 = be2[c] + (cb[c] - mu2[c]) * s2;
        #pragma unroll
        for (int m = 0; m < 4; ++m){
            #pragma unroll
            for (int r = 0; r < 4; ++r){
                int pos = m*16 + q*4 + r;
                int gx  = x0 + pos;
                size_t cell = (size_t)(b*Yq + y)*Xq + gx;
                float val = 0.f;
                if (act[cell]) val = fmaxf(fmaf(acc[m][n][r], s2, sh2), 0.f);
                out[cell*128 + c] = val;
            }
        }
    }
}

extern "C" void kernel_launch(void* const* d_in, const int* in_sizes, int n_in,
                              void* d_out, int out_size, void* d_ws, size_t ws_size,
                              hipStream_t stream){
    const float* vf  = (const float*)d_in[0];
    const int*   vc  = (const int*)  d_in[1];
    const float* Wp  = (const float*)d_in[2];
    const float* bp  = (const float*)d_in[3];
    const float* g1  = (const float*)d_in[4];
    const float* be1 = (const float*)d_in[5];
    const float* mu1 = (const float*)d_in[6];
    const float* va1 = (const float*)d_in[7];
    const float* cw  = (const float*)d_in[8];
    const float* cb  = (const float*)d_in[9];
    const float* g2  = (const float*)d_in[10];
    const float* be2 = (const float*)d_in[11];
    const float* mu2 = (const float*)d_in[12];
    const float* va2 = (const float*)d_in[13];
    float* out = (float*)d_out;
    char* ws = (char*)d_ws;

    // ws layout (bytes):
    //   dense fp32 [2][512][512][128]   : 268,435,456 @ 0
    //   dbf bf16   [2][514][514][128]   : 135,268,352 @ 268,435,456
    //   act  u8    [2][512][512]        :     524,288 @ 403,703,808
    //   wT   bf16  [9][128][128]        :     294,912 @ 404,228,096
    //   wpT  bf16  [128][192]           :      49,152 @ 404,523,008  (end 404,572,160)
    if (ws_size < 404572160ull) return;   // diagnostic: output stays poisoned
    float* dense = (float*)ws;
    short* dbf   = (short*)(ws + 268435456);
    unsigned char* act = (unsigned char*)(ws + 403703808);
    short* wT    = (short*)(ws + 404228096);
    short* wpT   = (short*)(ws + 404523008);

    hipMemsetAsync(dense, 0, 268435456, stream);
    hipMemsetAsync(act, 0, 524288, stream);
    kprep<<<672, 256, 0, stream>>>(cw, Wp, wT, wpT);
    kproj<<<6250, 256, 0, stream>>>(vf, vc, wpT, bp, g1, be1, mu1, va1, dense, act);
    kcvt<<<33025, 256, 0, stream>>>(dense, dbf);
    kconv<<<8192, 256, 0, stream>>>(dbf, wT, act, cb, g2, be2, mu2, va2, out);
}